// Round 2
// baseline (6281.817 us; speedup 1.0000x reference)
//
#include <hip/hip_runtime.h>
#include <math.h>

#define QL 4
#define BB 8
#define NN 4096
#define DIMF 1024
#define HH 8
#define CC 1024
#define DH 128

#define MARGIN 1e-3f

// ---------------------------------------------------------------------------
// Kernel A: k = codes @ wk, v = codes @ wv  per (q,h).  (fp32 fast path)
// ---------------------------------------------------------------------------
__global__ __launch_bounds__(128) void kv_kernel(
    const float* __restrict__ codes, const float* __restrict__ wk,
    const float* __restrict__ wv, float* __restrict__ kbuf,
    float* __restrict__ vbuf)
{
    __shared__ float sc[8][128];
    int bid = blockIdx.x;
    int cg  = bid & 127;
    int qh  = bid >> 7;
    int t   = threadIdx.x;

    const float* cbase = codes + ((size_t)qh * CC + (size_t)cg * 8) * DH;
    #pragma unroll
    for (int i = 0; i < 8; ++i) sc[i][t] = cbase[i * DH + t];
    __syncthreads();

    const float* wkb = wk + (size_t)qh * DH * DH;
    const float* wvb = wv + (size_t)qh * DH * DH;

    float ak[8], av[8];
    #pragma unroll
    for (int i = 0; i < 8; ++i) { ak[i] = 0.f; av[i] = 0.f; }

    for (int d = 0; d < DH; ++d) {
        float a = wkb[d * DH + t];
        float b = wvb[d * DH + t];
        #pragma unroll
        for (int i = 0; i < 8; ++i) {
            ak[i] = fmaf(sc[i][d], a, ak[i]);
            av[i] = fmaf(sc[i][d], b, av[i]);
        }
    }

    float* kb = kbuf + ((size_t)qh * CC + (size_t)cg * 8) * DH + t;
    float* vb = vbuf + ((size_t)qh * CC + (size_t)cg * 8) * DH + t;
    #pragma unroll
    for (int i = 0; i < 8; ++i) { kb[i * DH] = ak[i]; vb[i * DH] = av[i]; }
}

// ---------------------------------------------------------------------------
// Kernel B: fused 4-layer residual memcodes with f64 near-tie rescue.
// grid = B*H*(N/64) = 4096 blocks, 256 threads.
// ---------------------------------------------------------------------------
__global__ __launch_bounds__(256) void fused_kernel(
    const float* __restrict__ x, const float* __restrict__ kbuf,
    const float* __restrict__ vbuf, const float* __restrict__ codes,
    const float* __restrict__ wk, const float* __restrict__ wv,
    float* __restrict__ out)
{
    __shared__ float rT[DH][64];                    // residual [d][tok]
    __shared__ float kT[DH][64];                    // k tile  [d][code]
    __shared__ float smax[64][17];                  // col16 = final m1
    __shared__ __align__(16) float smax2[64][17];   // overlaid w/ rescue scratch
    __shared__ int   sidx[64][17];
    __shared__ int   chosen[64];
    __shared__ int   hist[QL][64];
    __shared__ int   flagged[64];

    // rescue scratch overlaid on smax2 (dead during rescue)
    double* rbuf  = (double*)&smax2[0][0];              // 128 doubles (1024B)
    double* pbuf  = (double*)((char*)&smax2[0][0] + 1024); // 128 doubles
    int*    cand  = (int*)((char*)&smax2[0][0] + 2048);    // 64 ints
    int*    ncand = (int*)((char*)&smax2[0][0] + 2304);
    int*    bestc = (int*)((char*)&smax2[0][0] + 2308);
    double* bestv = (double*)((char*)&smax2[0][0] + 2312);

    int bid = blockIdx.x;
    int nt  = bid & 63;
    int bh  = bid >> 6;
    int h   = bh & 7;
    int b   = bh >> 3;
    int n0  = nt * 64;
    int t   = threadIdx.x;

    const float* xbase = x + ((size_t)b * NN + n0) * DIMF + h * DH;

    // ---- init residual = x ----
    #pragma unroll
    for (int kk = 0; kk < 8; ++kk) {
        int g   = t + kk * 256;
        int tok = g >> 5;
        int dq  = g & 31;
        float4 v4 = *reinterpret_cast<const float4*>(xbase + (size_t)tok * DIMF + dq * 4);
        rT[dq * 4 + 0][tok] = v4.x;
        rT[dq * 4 + 1][tok] = v4.y;
        rT[dq * 4 + 2][tok] = v4.z;
        rT[dq * 4 + 3][tok] = v4.w;
    }

    int tx = t & 15;
    int ty = t >> 4;
    int cl = t & 63;
    int dg = t >> 6;

    for (int q = 0; q < QL; ++q) {
        const float* kq = kbuf + ((size_t)q * HH + h) * CC * DH;
        const float* vq = vbuf + ((size_t)q * HH + h) * CC * DH;

        float bv0 = -INFINITY, bv1 = -INFINITY, bv2 = -INFINITY, bv3 = -INFINITY;
        float c0v = -INFINITY, c1v = -INFINITY, c2v = -INFINITY, c3v = -INFINITY; // 2nd max
        int   bi0 = 0, bi1 = 0, bi2 = 0, bi3 = 0;

        for (int ct = 0; ct < 16; ++ct) {
            __syncthreads();
            // ---- stage 64x128 k tile, transposed ----
            {
                const float* krow = kq + ((size_t)ct * 64 + cl) * DH + dg * 32;
                #pragma unroll
                for (int j = 0; j < 8; ++j) {
                    float4 v4 = *reinterpret_cast<const float4*>(krow + j * 4);
                    int d = dg * 32 + j * 4;
                    kT[d + 0][cl] = v4.x;
                    kT[d + 1][cl] = v4.y;
                    kT[d + 2][cl] = v4.z;
                    kT[d + 3][cl] = v4.w;
                }
            }
            __syncthreads();

            // ---- 64x64 logits, 4x4 micro-tile ----
            float s00 = 0.f, s01 = 0.f, s02 = 0.f, s03 = 0.f;
            float s10 = 0.f, s11 = 0.f, s12 = 0.f, s13 = 0.f;
            float s20 = 0.f, s21 = 0.f, s22 = 0.f, s23 = 0.f;
            float s30 = 0.f, s31 = 0.f, s32 = 0.f, s33 = 0.f;

            #pragma unroll 16
            for (int d = 0; d < DH; ++d) {
                float4 rv = *reinterpret_cast<const float4*>(&rT[d][ty * 4]);
                float4 kv = *reinterpret_cast<const float4*>(&kT[d][tx * 4]);
                s00 = fmaf(rv.x, kv.x, s00); s01 = fmaf(rv.x, kv.y, s01);
                s02 = fmaf(rv.x, kv.z, s02); s03 = fmaf(rv.x, kv.w, s03);
                s10 = fmaf(rv.y, kv.x, s10); s11 = fmaf(rv.y, kv.y, s11);
                s12 = fmaf(rv.y, kv.z, s12); s13 = fmaf(rv.y, kv.w, s13);
                s20 = fmaf(rv.z, kv.x, s20); s21 = fmaf(rv.z, kv.y, s21);
                s22 = fmaf(rv.z, kv.z, s22); s23 = fmaf(rv.z, kv.w, s23);
                s30 = fmaf(rv.w, kv.x, s30); s31 = fmaf(rv.w, kv.y, s31);
                s32 = fmaf(rv.w, kv.z, s32); s33 = fmaf(rv.w, kv.w, s33);
            }

            int cb = ct * 64 + tx * 4;
            // token 0 (strict > keeps first index; 2nd-max tracked incl. ties)
            if (s00 > bv0) { c0v = bv0; bv0 = s00; bi0 = cb + 0; } else if (s00 > c0v) c0v = s00;
            if (s01 > bv0) { c0v = bv0; bv0 = s01; bi0 = cb + 1; } else if (s01 > c0v) c0v = s01;
            if (s02 > bv0) { c0v = bv0; bv0 = s02; bi0 = cb + 2; } else if (s02 > c0v) c0v = s02;
            if (s03 > bv0) { c0v = bv0; bv0 = s03; bi0 = cb + 3; } else if (s03 > c0v) c0v = s03;
            // token 1
            if (s10 > bv1) { c1v = bv1; bv1 = s10; bi1 = cb + 0; } else if (s10 > c1v) c1v = s10;
            if (s11 > bv1) { c1v = bv1; bv1 = s11; bi1 = cb + 1; } else if (s11 > c1v) c1v = s11;
            if (s12 > bv1) { c1v = bv1; bv1 = s12; bi1 = cb + 2; } else if (s12 > c1v) c1v = s12;
            if (s13 > bv1) { c1v = bv1; bv1 = s13; bi1 = cb + 3; } else if (s13 > c1v) c1v = s13;
            // token 2
            if (s20 > bv2) { c2v = bv2; bv2 = s20; bi2 = cb + 0; } else if (s20 > c2v) c2v = s20;
            if (s21 > bv2) { c2v = bv2; bv2 = s21; bi2 = cb + 1; } else if (s21 > c2v) c2v = s21;
            if (s22 > bv2) { c2v = bv2; bv2 = s22; bi2 = cb + 2; } else if (s22 > c2v) c2v = s22;
            if (s23 > bv2) { c2v = bv2; bv2 = s23; bi2 = cb + 3; } else if (s23 > c2v) c2v = s23;
            // token 3
            if (s30 > bv3) { c3v = bv3; bv3 = s30; bi3 = cb + 0; } else if (s30 > c3v) c3v = s30;
            if (s31 > bv3) { c3v = bv3; bv3 = s31; bi3 = cb + 1; } else if (s31 > c3v) c3v = s31;
            if (s32 > bv3) { c3v = bv3; bv3 = s32; bi3 = cb + 2; } else if (s32 > c3v) c3v = s32;
            if (s33 > bv3) { c3v = bv3; bv3 = s33; bi3 = cb + 3; } else if (s33 > c3v) c3v = s33;
        }

        // ---- cross-thread argmax + gap reduce ----
        smax[ty * 4 + 0][tx] = bv0; sidx[ty * 4 + 0][tx] = bi0; smax2[ty * 4 + 0][tx] = c0v;
        smax[ty * 4 + 1][tx] = bv1; sidx[ty * 4 + 1][tx] = bi1; smax2[ty * 4 + 1][tx] = c1v;
        smax[ty * 4 + 2][tx] = bv2; sidx[ty * 4 + 2][tx] = bi2; smax2[ty * 4 + 2][tx] = c2v;
        smax[ty * 4 + 3][tx] = bv3; sidx[ty * 4 + 3][tx] = bi3; smax2[ty * 4 + 3][tx] = c3v;
        __syncthreads();

        if (t < 64) {
            float m = smax[t][0]; int mi = sidx[t][0]; float m2 = smax2[t][0];
            #pragma unroll
            for (int j = 1; j < 16; ++j) {
                float v1 = smax[t][j]; int i1 = sidx[t][j]; float v2 = smax2[t][j];
                if (v1 > m) { m2 = fmaxf(m, v2); m = v1; mi = i1; }
                else {
                    if (v1 == m && i1 < mi) mi = i1;
                    m2 = fmaxf(m2, v1);
                }
            }
            chosen[t]  = mi;
            smax[t][16] = m;                       // save m1 for rescue
            flagged[t] = (m - m2 < MARGIN) ? 1 : 0;
        }
        __syncthreads();

        // ---- f64 rescue for near-tie tokens (rare; uniform branches) ----
        for (int tok = 0; tok < 64; ++tok) {
            if (!flagged[tok]) continue;
            if (t == 0) { *ncand = 0; *bestc = 0x7fffffff; *bestv = -1e300; }
            __syncthreads();

            // (a) rescan fp32 logits of this token (bitwise-same op order)
            float thr = smax[tok][16] - MARGIN;
            #pragma unroll
            for (int cc = 0; cc < 4; ++cc) {
                int c = t * 4 + cc;
                const float* krow = kq + (size_t)c * DH;
                float acc = 0.f;
                for (int d = 0; d < DH; d += 4) {
                    float4 k4 = *reinterpret_cast<const float4*>(krow + d);
                    acc = fmaf(rT[d + 0][tok], k4.x, acc);
                    acc = fmaf(rT[d + 1][tok], k4.y, acc);
                    acc = fmaf(rT[d + 2][tok], k4.z, acc);
                    acc = fmaf(rT[d + 3][tok], k4.w, acc);
                }
                if (acc >= thr) {
                    int p = atomicAdd(ncand, 1);
                    if (p < 64) cand[p] = c;
                }
            }
            __syncthreads();

            // (b) exact f64 residual for this token from x, codes, wv, history
            if (t < DH) {
                double r = (double)xbase[(size_t)tok * DIMF + t];
                for (int qq = 0; qq < q; ++qq) {
                    int c = hist[qq][tok];
                    const float* crow = codes + ((size_t)(qq * HH + h) * CC + c) * DH;
                    const float* wcol = wv + (size_t)(qq * HH + h) * DH * DH + t;
                    double acc = 0.0;
                    for (int dd = 0; dd < DH; ++dd)
                        acc += (double)crow[dd] * (double)wcol[(size_t)dd * DH];
                    r -= acc;
                }
                rbuf[t] = r;
            }
            __syncthreads();

            // (c) f64 rescore of candidates (on-the-fly f64 k rows)
            int nc = *ncand; if (nc > 64) nc = 64;
            for (int ci = 0; ci < nc; ++ci) {
                int c = cand[ci];
                if (t < DH) {
                    const float* crow = codes + ((size_t)(q * HH + h) * CC + c) * DH;
                    const float* wcol = wk + (size_t)(q * HH + h) * DH * DH + t;
                    double acc = 0.0;
                    for (int dd = 0; dd < DH; ++dd)
                        acc += (double)crow[dd] * (double)wcol[(size_t)dd * DH];
                    pbuf[t] = acc * rbuf[t];
                }
                __syncthreads();
                if (t == 0) {
                    double s = 0.0;
                    for (int dd = 0; dd < DH; ++dd) s += pbuf[dd];
                    if (s > *bestv || (s == *bestv && c < *bestc)) { *bestv = s; *bestc = c; }
                }
                __syncthreads();
            }
            if (t == 0) chosen[tok] = *bestc;
            __syncthreads();
        }

        // ---- finalize indices: history + output ----
        if (t < 64) {
            int mi = chosen[t];
            hist[q][t] = mi;
            out[(size_t)BB * NN * DIMF +
                (((size_t)(b * HH + h) * NN) + n0 + t) * QL + q] = (float)mi;
        }
        __syncthreads();

        // ---- residual -= v[chosen] ----
        {
            const float* vrow = vq + (size_t)chosen[cl] * DH + dg * 32;
            #pragma unroll
            for (int j = 0; j < 8; ++j) {
                float4 v4 = *reinterpret_cast<const float4*>(vrow + j * 4);
                int d = dg * 32 + j * 4;
                rT[d + 0][cl] -= v4.x;
                rT[d + 1][cl] -= v4.y;
                rT[d + 2][cl] -= v4.z;
                rT[d + 3][cl] -= v4.w;
            }
        }
    }

    __syncthreads();
    // ---- epilogue: quantized_out = x - residual ----
    #pragma unroll
    for (int kk = 0; kk < 8; ++kk) {
        int g   = t + kk * 256;
        int tok = g >> 5;
        int dq  = g & 31;
        float4 xv = *reinterpret_cast<const float4*>(xbase + (size_t)tok * DIMF + dq * 4);
        float4 ov;
        ov.x = xv.x - rT[dq * 4 + 0][tok];
        ov.y = xv.y - rT[dq * 4 + 1][tok];
        ov.z = xv.z - rT[dq * 4 + 2][tok];
        ov.w = xv.w - rT[dq * 4 + 3][tok];
        *reinterpret_cast<float4*>(out + ((size_t)b * NN + n0 + tok) * DIMF + h * DH + dq * 4) = ov;
    }
}

extern "C" void kernel_launch(void* const* d_in, const int* in_sizes, int n_in,
                              void* d_out, int out_size, void* d_ws, size_t ws_size,
                              hipStream_t stream) {
    const float* x     = (const float*)d_in[0];
    const float* codes = (const float*)d_in[1];
    const float* wk    = (const float*)d_in[2];
    const float* wv    = (const float*)d_in[3];
    float* out  = (float*)d_out;
    float* kbuf = (float*)d_ws;
    float* vbuf = kbuf + (size_t)QL * HH * CC * DH;

    kv_kernel<<<QL * HH * CC / 8, 128, 0, stream>>>(codes, wk, wv, kbuf, vbuf);
    fused_kernel<<<BB * HH * (NN / 64), 256, 0, stream>>>(x, kbuf, vbuf, codes, wk, wv, out);
}

// Round 3
// 1493.902 us; speedup vs baseline: 4.2050x; 4.2050x over previous
//
#include <hip/hip_runtime.h>
#include <math.h>

#define QL 4
#define BB 8
#define NN 4096
#define DIMF 1024
#define HH 8
#define CC 1024
#define DH 128

#define MARGIN 1e-3f

typedef __attribute__((ext_vector_type(4))) float f32x4;
typedef __attribute__((ext_vector_type(8))) short s16x8;
typedef __attribute__((ext_vector_type(4))) int i32x4;

__device__ __forceinline__ unsigned short f2bf(float f) {
    unsigned int u = __float_as_uint(f);
    u = u + 0x7fffu + ((u >> 16) & 1u);
    return (unsigned short)(u >> 16);
}
__device__ __forceinline__ float bf2f(unsigned short b) {
    return __uint_as_float(((unsigned int)b) << 16);
}

// ---------------------------------------------------------------------------
// Kernel A: k = codes @ wk (split to bf16 hi/lo), v = codes @ wv (f32).
// grid = Q*H*C/8 = 4096 blocks, 128 threads.
// ---------------------------------------------------------------------------
__global__ __launch_bounds__(128) void kv_kernel(
    const float* __restrict__ codes, const float* __restrict__ wk,
    const float* __restrict__ wv, unsigned short* __restrict__ khi,
    unsigned short* __restrict__ klo, float* __restrict__ vbuf)
{
    __shared__ float sc[8][128];
    int bid = blockIdx.x;
    int cg  = bid & 127;
    int qh  = bid >> 7;
    int t   = threadIdx.x;

    const float* cbase = codes + ((size_t)qh * CC + (size_t)cg * 8) * DH;
    #pragma unroll
    for (int i = 0; i < 8; ++i) sc[i][t] = cbase[i * DH + t];
    __syncthreads();

    const float* wkb = wk + (size_t)qh * DH * DH;
    const float* wvb = wv + (size_t)qh * DH * DH;

    float ak[8], av[8];
    #pragma unroll
    for (int i = 0; i < 8; ++i) { ak[i] = 0.f; av[i] = 0.f; }

    for (int d = 0; d < DH; ++d) {
        float a = wkb[d * DH + t];
        float b = wvb[d * DH + t];
        #pragma unroll
        for (int i = 0; i < 8; ++i) {
            ak[i] = fmaf(sc[i][d], a, ak[i]);
            av[i] = fmaf(sc[i][d], b, av[i]);
        }
    }

    size_t base = ((size_t)qh * CC + (size_t)cg * 8) * DH + t;
    #pragma unroll
    for (int i = 0; i < 8; ++i) {
        float f = ak[i];
        unsigned short hb = f2bf(f);
        unsigned short lb = f2bf(f - bf2f(hb));
        khi[base + (size_t)i * DH] = hb;
        klo[base + (size_t)i * DH] = lb;
        vbuf[base + (size_t)i * DH] = av[i];
    }
}

// ---------------------------------------------------------------------------
// Kernel B: fused 4-layer residual memcodes, MFMA bf16-split logits.
// grid = B*H*(N/128) = 2048 blocks, 256 threads (4 waves).
// Wave w owns token tiles tt0=w, tt1=w+4 (A-frag layout, residual in regs).
// ---------------------------------------------------------------------------
__global__ __launch_bounds__(256, 2) void fused_kernel(
    const float* __restrict__ x, const unsigned short* __restrict__ khi,
    const unsigned short* __restrict__ klo, const float* __restrict__ vbuf,
    const float* __restrict__ codes, const float* __restrict__ wk,
    const float* __restrict__ wv, float* __restrict__ out)
{
    __shared__ unsigned char kstage[2][32768];   // [buf][hi 16K | lo 16K], swizzled
    __shared__ int    chosen[128];
    __shared__ float  smax1[128];
    __shared__ int    flagged[128];
    __shared__ int    hist[QL][128];
    __shared__ int    nflag;
    __shared__ float  rbuf32[128];
    __shared__ double rbuf64[128];
    __shared__ double pbuf[128];
    __shared__ int    cand[64];
    __shared__ int    ncand;
    __shared__ int    bestc;
    __shared__ double bestv;

    const int t  = threadIdx.x;
    const int w  = t >> 6;
    const int l  = t & 63;
    const int lr = l & 15;
    const int lg = l >> 4;

    const int bid = blockIdx.x;
    const int nt = bid & 31;
    const int h  = (bid >> 5) & 7;
    const int b  = bid >> 8;
    const int n0 = nt * 128;

    const int tok0 = w * 16 + lr;
    const int tok1 = (w + 4) * 16 + lr;

    const float* x0 = x + ((size_t)(b * NN + n0 + tok0)) * DIMF + h * DH;
    const float* x1 = x + ((size_t)(b * NN + n0 + tok1)) * DIMF + h * DH;

    float res0[4][8], res1[4][8];
    #pragma unroll
    for (int ks = 0; ks < 4; ++ks) {
        const int dh0 = ks * 32 + lg * 8;
        float4 a0 = *reinterpret_cast<const float4*>(x0 + dh0);
        float4 a1 = *reinterpret_cast<const float4*>(x0 + dh0 + 4);
        float4 c0 = *reinterpret_cast<const float4*>(x1 + dh0);
        float4 c1 = *reinterpret_cast<const float4*>(x1 + dh0 + 4);
        res0[ks][0] = a0.x; res0[ks][1] = a0.y; res0[ks][2] = a0.z; res0[ks][3] = a0.w;
        res0[ks][4] = a1.x; res0[ks][5] = a1.y; res0[ks][6] = a1.z; res0[ks][7] = a1.w;
        res1[ks][0] = c0.x; res1[ks][1] = c0.y; res1[ks][2] = c0.z; res1[ks][3] = c0.w;
        res1[ks][4] = c1.x; res1[ks][5] = c1.y; res1[ks][6] = c1.z; res1[ks][7] = c1.w;
    }

    if (t == 0) nflag = 0;

    const int sc_c = t >> 2;        // staging: code row 0..63
    const int sc_p = t & 3;         // staging: 64B segment

    for (int q = 0; q < QL; ++q) {
        const unsigned short* khq = khi + (size_t)(q * 8 + h) * CC * DH;
        const unsigned short* klq = klo + (size_t)(q * 8 + h) * CC * DH;
        const float* vq = vbuf + (size_t)(q * 8 + h) * CC * DH;

        // ---- split residual to bf16 hi/lo A-fragments ----
        s16x8 ahi0[4], alo0[4], ahi1[4], alo1[4];
        #pragma unroll
        for (int ks = 0; ks < 4; ++ks) {
            s16x8 h0, l0, h1, l1;
            #pragma unroll
            for (int j = 0; j < 8; ++j) {
                float f = res0[ks][j];
                unsigned short hb = f2bf(f);
                unsigned short lb = f2bf(f - bf2f(hb));
                h0[j] = (short)hb; l0[j] = (short)lb;
                f = res1[ks][j];
                hb = f2bf(f);
                lb = f2bf(f - bf2f(hb));
                h1[j] = (short)hb; l1[j] = (short)lb;
            }
            ahi0[ks] = h0; alo0[ks] = l0; ahi1[ks] = h1; alo1[ks] = l1;
        }

        float bvA[4], b2A[4], bvB[4], b2B[4];
        int   biA[4], biB[4];
        #pragma unroll
        for (int r = 0; r < 4; ++r) {
            bvA[r] = -INFINITY; b2A[r] = -INFINITY; biA[r] = 0;
            bvB[r] = -INFINITY; b2B[r] = -INFINITY; biB[r] = 0;
        }

        // ---- prologue: stage chunk 0 into buf 0 ----
        {
            const size_t rowbase = (size_t)sc_c * DH + sc_p * 32;
            i32x4 st[8];
            #pragma unroll
            for (int jj = 0; jj < 4; ++jj) {
                st[jj]     = *reinterpret_cast<const i32x4*>(khq + rowbase + jj * 8);
                st[4 + jj] = *reinterpret_cast<const i32x4*>(klq + rowbase + jj * 8);
            }
            #pragma unroll
            for (int jj = 0; jj < 4; ++jj) {
                int o = (sc_c * 256 + sc_p * 64 + jj * 16) ^ ((sc_c & 7) << 4);
                *reinterpret_cast<i32x4*>(&kstage[0][o])         = st[jj];
                *reinterpret_cast<i32x4*>(&kstage[0][16384 + o]) = st[4 + jj];
            }
        }
        __syncthreads();

        // ---- chunk loop: 16 x 64 codes ----
        for (int ct = 0; ct < 16; ++ct) {
            const int cur = ct & 1;
            i32x4 st[8];
            if (ct < 15) {
                const size_t rowbase = (size_t)((ct + 1) * 64 + sc_c) * DH + sc_p * 32;
                #pragma unroll
                for (int jj = 0; jj < 4; ++jj) {
                    st[jj]     = *reinterpret_cast<const i32x4*>(khq + rowbase + jj * 8);
                    st[4 + jj] = *reinterpret_cast<const i32x4*>(klq + rowbase + jj * 8);
                }
            }

            #pragma unroll
            for (int ctile = 0; ctile < 4; ++ctile) {
                f32x4 acc0 = {0.f, 0.f, 0.f, 0.f};
                f32x4 acc1 = {0.f, 0.f, 0.f, 0.f};
                #pragma unroll
                for (int ks = 0; ks < 4; ++ks) {
                    int o = (((ctile * 16 + lr) * 256 + ks * 64 + lg * 16)
                             ^ ((lr & 7) << 4));
                    s16x8 bh = *reinterpret_cast<const s16x8*>(&kstage[cur][o]);
                    s16x8 bl = *reinterpret_cast<const s16x8*>(&kstage[cur][16384 + o]);
                    acc0 = __builtin_amdgcn_mfma_f32_16x16x32_bf16(ahi0[ks], bh, acc0, 0, 0, 0);
                    acc1 = __builtin_amdgcn_mfma_f32_16x16x32_bf16(ahi1[ks], bh, acc1, 0, 0, 0);
                    acc0 = __builtin_amdgcn_mfma_f32_16x16x32_bf16(alo0[ks], bh, acc0, 0, 0, 0);
                    acc1 = __builtin_amdgcn_mfma_f32_16x16x32_bf16(alo1[ks], bh, acc1, 0, 0, 0);
                    acc0 = __builtin_amdgcn_mfma_f32_16x16x32_bf16(ahi0[ks], bl, acc0, 0, 0, 0);
                    acc1 = __builtin_amdgcn_mfma_f32_16x16x32_bf16(ahi1[ks], bl, acc1, 0, 0, 0);
                }
                const int cbase = ct * 64 + ctile * 16 + lr;
                #pragma unroll
                for (int r = 0; r < 4; ++r) {
                    float v0 = acc0[r], v1 = acc1[r];
                    if (v0 > bvA[r]) { b2A[r] = bvA[r]; bvA[r] = v0; biA[r] = cbase; }
                    else if (v0 > b2A[r]) b2A[r] = v0;
                    if (v1 > bvB[r]) { b2B[r] = bvB[r]; bvB[r] = v1; biB[r] = cbase; }
                    else if (v1 > b2B[r]) b2B[r] = v1;
                }
            }

            if (ct < 15) {
                #pragma unroll
                for (int jj = 0; jj < 4; ++jj) {
                    int o = (sc_c * 256 + sc_p * 64 + jj * 16) ^ ((sc_c & 7) << 4);
                    *reinterpret_cast<i32x4*>(&kstage[cur ^ 1][o])         = st[jj];
                    *reinterpret_cast<i32x4*>(&kstage[cur ^ 1][16384 + o]) = st[4 + jj];
                }
            }
            __syncthreads();
        }

        // ---- cross-lane argmax reduce (16 lanes per token row) ----
        #pragma unroll
        for (int r = 0; r < 4; ++r) {
            #pragma unroll
            for (int off = 1; off <= 8; off <<= 1) {
                float ov = __shfl_xor(bvA[r], off);
                int   oi = __shfl_xor(biA[r], off);
                float o2 = __shfl_xor(b2A[r], off);
                float nm2 = fmaxf(fmaxf(b2A[r], o2), fminf(bvA[r], ov));
                if (ov > bvA[r] || (ov == bvA[r] && oi < biA[r])) { bvA[r] = ov; biA[r] = oi; }
                b2A[r] = nm2;
                ov = __shfl_xor(bvB[r], off);
                oi = __shfl_xor(biB[r], off);
                o2 = __shfl_xor(b2B[r], off);
                nm2 = fmaxf(fmaxf(b2B[r], o2), fminf(bvB[r], ov));
                if (ov > bvB[r] || (ov == bvB[r] && oi < biB[r])) { bvB[r] = ov; biB[r] = oi; }
                b2B[r] = nm2;
            }
        }
        if (lr == 0) {
            #pragma unroll
            for (int r = 0; r < 4; ++r) {
                int ta = w * 16 + lg * 4 + r;
                chosen[ta] = biA[r]; smax1[ta] = bvA[r];
                int fa = (bvA[r] - b2A[r] < MARGIN) ? 1 : 0;
                flagged[ta] = fa;
                if (fa) atomicAdd(&nflag, 1);
                int tb = (w + 4) * 16 + lg * 4 + r;
                chosen[tb] = biB[r]; smax1[tb] = bvB[r];
                int fb = (bvB[r] - b2B[r] < MARGIN) ? 1 : 0;
                flagged[tb] = fb;
                if (fb) atomicAdd(&nflag, 1);
            }
        }
        __syncthreads();

        // ---- f64 rescue for near-tie tokens (rare) ----
        int nf = nflag;
        if (nf) {
            for (int tok = 0; tok < 128; ++tok) {
                if (!flagged[tok]) continue;
                // rebuild fp32 residual of this token into rbuf32
                {
                    int tw = tok >> 4;
                    if (w == (tw & 3) && lr == (tok & 15)) {
                        if (tw < 4) {
                            #pragma unroll
                            for (int ks = 0; ks < 4; ++ks)
                                #pragma unroll
                                for (int j = 0; j < 8; ++j)
                                    rbuf32[ks * 32 + lg * 8 + j] = res0[ks][j];
                        } else {
                            #pragma unroll
                            for (int ks = 0; ks < 4; ++ks)
                                #pragma unroll
                                for (int j = 0; j < 8; ++j)
                                    rbuf32[ks * 32 + lg * 8 + j] = res1[ks][j];
                        }
                    }
                }
                if (t == 0) { ncand = 0; bestc = 0x7fffffff; bestv = -1e300; }
                __syncthreads();

                // (a) fp32 prescan: collect candidates within MARGIN of m1
                float thr = smax1[tok] - MARGIN;
                #pragma unroll
                for (int cc4 = 0; cc4 < 4; ++cc4) {
                    int c = t * 4 + cc4;
                    const unsigned short* kh = khq + (size_t)c * DH;
                    const unsigned short* kl = klq + (size_t)c * DH;
                    float acc = 0.f;
                    for (int d = 0; d < DH; ++d)
                        acc = fmaf(bf2f(kh[d]) + bf2f(kl[d]), rbuf32[d], acc);
                    if (acc >= thr) {
                        int p = atomicAdd(&ncand, 1);
                        if (p < 64) cand[p] = c;
                    }
                }
                __syncthreads();

                // (b) exact f64 residual from x, codes, wv, history
                if (t < DH) {
                    double r = (double)x[((size_t)(b * NN + n0 + tok)) * DIMF + h * DH + t];
                    for (int qq = 0; qq < q; ++qq) {
                        int c = hist[qq][tok];
                        const float* crow = codes + ((size_t)(qq * 8 + h) * CC + c) * DH;
                        const float* wcol = wv + (size_t)(qq * 8 + h) * DH * DH + t;
                        double acc = 0.0;
                        for (int dd = 0; dd < DH; ++dd)
                            acc += (double)crow[dd] * (double)wcol[(size_t)dd * DH];
                        r -= acc;
                    }
                    rbuf64[t] = r;
                }
                __syncthreads();

                // (c) f64 rescore of candidates
                int nc = ncand; if (nc > 64) nc = 64;
                for (int ci = 0; ci < nc; ++ci) {
                    int c = cand[ci];
                    if (t < DH) {
                        const float* crow = codes + ((size_t)(q * 8 + h) * CC + c) * DH;
                        const float* wcol = wk + (size_t)(q * 8 + h) * DH * DH + t;
                        double acc = 0.0;
                        for (int dd = 0; dd < DH; ++dd)
                            acc += (double)crow[dd] * (double)wcol[(size_t)dd * DH];
                        pbuf[t] = acc * rbuf64[t];
                    }
                    __syncthreads();
                    if (t == 0) {
                        double s = 0.0;
                        for (int dd = 0; dd < DH; ++dd) s += pbuf[dd];
                        if (s > bestv || (s == bestv && c < bestc)) { bestv = s; bestc = c; }
                    }
                    __syncthreads();
                }
                if (t == 0) chosen[tok] = bestc;
                __syncthreads();
            }
        }

        // ---- finalize: history + idx output; reset flag counter ----
        if (t < 128) {
            int mi = chosen[t];
            hist[q][t] = mi;
            out[(size_t)BB * NN * DIMF +
                (((size_t)(b * HH + h) * NN) + n0 + t) * QL + q] = (float)mi;
        }
        if (t == 0) nflag = 0;

        // ---- residual -= v[chosen] (regs; chosen stable since last barrier) ----
        {
            const float* v0p = vq + (size_t)chosen[tok0] * DH;
            const float* v1p = vq + (size_t)chosen[tok1] * DH;
            #pragma unroll
            for (int ks = 0; ks < 4; ++ks) {
                const int dh0 = ks * 32 + lg * 8;
                float4 a0 = *reinterpret_cast<const float4*>(v0p + dh0);
                float4 a1 = *reinterpret_cast<const float4*>(v0p + dh0 + 4);
                float4 c0 = *reinterpret_cast<const float4*>(v1p + dh0);
                float4 c1 = *reinterpret_cast<const float4*>(v1p + dh0 + 4);
                res0[ks][0] -= a0.x; res0[ks][1] -= a0.y; res0[ks][2] -= a0.z; res0[ks][3] -= a0.w;
                res0[ks][4] -= a1.x; res0[ks][5] -= a1.y; res0[ks][6] -= a1.z; res0[ks][7] -= a1.w;
                res1[ks][0] -= c0.x; res1[ks][1] -= c0.y; res1[ks][2] -= c0.z; res1[ks][3] -= c0.w;
                res1[ks][4] -= c1.x; res1[ks][5] -= c1.y; res1[ks][6] -= c1.z; res1[ks][7] -= c1.w;
            }
        }
        __syncthreads();   // chosen reads done before next layer's writers
    }

    // ---- epilogue: quantized_out = x - residual ----
    #pragma unroll
    for (int ks = 0; ks < 4; ++ks) {
        const int dh0 = ks * 32 + lg * 8;
        float4 a0 = *reinterpret_cast<const float4*>(x0 + dh0);
        float4 a1 = *reinterpret_cast<const float4*>(x0 + dh0 + 4);
        float4 c0 = *reinterpret_cast<const float4*>(x1 + dh0);
        float4 c1 = *reinterpret_cast<const float4*>(x1 + dh0 + 4);
        float4 o0, o1, o2, o3;
        o0.x = a0.x - res0[ks][0]; o0.y = a0.y - res0[ks][1];
        o0.z = a0.z - res0[ks][2]; o0.w = a0.w - res0[ks][3];
        o1.x = a1.x - res0[ks][4]; o1.y = a1.y - res0[ks][5];
        o1.z = a1.z - res0[ks][6]; o1.w = a1.w - res0[ks][7];
        o2.x = c0.x - res1[ks][0]; o2.y = c0.y - res1[ks][1];
        o2.z = c0.z - res1[ks][2]; o2.w = c0.w - res1[ks][3];
        o3.x = c1.x - res1[ks][4]; o3.y = c1.y - res1[ks][5];
        o3.z = c1.z - res1[ks][6]; o3.w = c1.w - res1[ks][7];
        float* ob0 = out + ((size_t)(b * NN + n0 + tok0)) * DIMF + h * DH + dh0;
        float* ob1 = out + ((size_t)(b * NN + n0 + tok1)) * DIMF + h * DH + dh0;
        *reinterpret_cast<float4*>(ob0)     = o0;
        *reinterpret_cast<float4*>(ob0 + 4) = o1;
        *reinterpret_cast<float4*>(ob1)     = o2;
        *reinterpret_cast<float4*>(ob1 + 4) = o3;
    }
}

extern "C" void kernel_launch(void* const* d_in, const int* in_sizes, int n_in,
                              void* d_out, int out_size, void* d_ws, size_t ws_size,
                              hipStream_t stream) {
    const float* x     = (const float*)d_in[0];
    const float* codes = (const float*)d_in[1];
    const float* wk    = (const float*)d_in[2];
    const float* wv    = (const float*)d_in[3];
    float* out  = (float*)d_out;

    float* vbuf = (float*)d_ws;                                   // 16 MiB
    unsigned short* khi = (unsigned short*)(vbuf + (size_t)QL * HH * CC * DH); // 8 MiB
    unsigned short* klo = khi + (size_t)QL * HH * CC * DH;        // 8 MiB

    kv_kernel<<<QL * HH * CC / 8, 128, 0, stream>>>(codes, wk, wv, khi, klo, vbuf);
    fused_kernel<<<BB * HH * (NN / 128), 256, 0, stream>>>(x, khi, klo, vbuf,
                                                           codes, wk, wv, out);
}